// Round 2
// baseline (1881.465 us; speedup 1.0000x reference)
//
#include <hip/hip_runtime.h>
#include <hip/hip_bf16.h>

// BiLSTM: B=64, T=2048, F=128, U=128. fp32 in/out.
// Phase 1: zx[d][bg][t][g][w][L] (f16) = x@Wx + b, L = m*16+ulocal (m=b&3).
// Phase 2: 64 WGs (2 dir x 32 batch-PAIRS), 4 waves each (1 wave/SIMD); per
//          step ONE lgkm-only barrier (inline asm) so zx prefetch stays in
//          flight. In-wave gates + row-replicated h => no z exchange,
//          1 cell/lane, 2 col-tiles/gate per wave.

typedef _Float16 half8_t __attribute__((ext_vector_type(8)));
typedef _Float16 half4_t __attribute__((ext_vector_type(4)));
typedef float floatx4 __attribute__((ext_vector_type(4)));

#define T_SEQ 2048
#define GDIM 512

__device__ __forceinline__ float sigm_f(float x) {
    return __builtin_amdgcn_rcpf(1.0f + __expf(-x));
}
__device__ __forceinline__ float tanh_f(float x) {
    return 1.0f - 2.0f * __builtin_amdgcn_rcpf(1.0f + __expf(2.0f * x));
}
// pick accumulator element for (col-tile ct, batch-parity p); rows are
// batch-replicated mod 2, so reg index p of tile ct holds this lane's cell.
__device__ __forceinline__ float selz(floatx4 v0, floatx4 v1, int ct, int p) {
    float a = p ? v0[1] : v0[0];
    float b = p ? v1[1] : v1[0];
    return ct ? b : a;
}

// ---------------- Phase 1: Zx GEMM (unchanged) ----------------
// grid: (32 ttiles, 64 batches, 2 dirs), block 256. A staged once; 4 ctile passes.
__global__ __launch_bounds__(256) void zx_gemm(
    const float* __restrict__ x,
    const float* __restrict__ Wfw, const float* __restrict__ bfw,
    const float* __restrict__ Wbw, const float* __restrict__ bbw,
    _Float16* __restrict__ zx) {
    const int tid = threadIdx.x;
    const int tt = blockIdx.x;           // 0..31
    const int b = blockIdx.y;            // batch
    const int d = blockIdx.z;            // dir
    const int t0 = tt * 64;
    const float* W = d ? Wbw : Wfw;
    const float* bias = d ? bbw : bfw;
    const int bg = b >> 2, m = b & 3;

    __shared__ _Float16 lA[64 * 136];
    __shared__ _Float16 lB[128 * 136];

    // stage A = x[b, t0..t0+63, 0..127] -> lA[row][k]
    const float* xp = x + ((size_t)b * T_SEQ + t0) * 128;
    for (int i = 0; i < 8; ++i) {
        int v = i * 256 + tid;
        int r = v >> 5;
        int kq = (v & 31) << 2;
        float4 f = *(const float4*)(xp + r * 128 + kq);
        half4_t h4;
        h4[0] = (_Float16)f.x; h4[1] = (_Float16)f.y;
        h4[2] = (_Float16)f.z; h4[3] = (_Float16)f.w;
        *(half4_t*)&lA[r * 136 + kq] = h4;
    }

    const int w1 = tid >> 6, lane = tid & 63, lm = lane & 15, q = lane >> 4;

    for (int ct = 0; ct < 4; ++ct) {
        // stage B = W[0..127, ct*128 .. +128) transposed -> lB[col][k]
        const float* wp = W + ct * 128;
        for (int i = 0; i < 16; ++i) {
            int v = i * 256 + tid;
            int k = v >> 5;
            int cq = (v & 31) << 2;
            float4 f = *(const float4*)(wp + (size_t)k * GDIM + cq);
            lB[(cq + 0) * 136 + k] = (_Float16)f.x;
            lB[(cq + 1) * 136 + k] = (_Float16)f.y;
            lB[(cq + 2) * 136 + k] = (_Float16)f.z;
            lB[(cq + 3) * 136 + k] = (_Float16)f.w;
        }
        __syncthreads();

        floatx4 acc[8];
#pragma unroll
        for (int nt = 0; nt < 8; ++nt) acc[nt] = (floatx4){0.f, 0.f, 0.f, 0.f};
#pragma unroll
        for (int ks = 0; ks < 4; ++ks) {
            const int k0 = ks * 32 + q * 8;
            half8_t a = *(const half8_t*)&lA[(w1 * 16 + lm) * 136 + k0];
#pragma unroll
            for (int nt = 0; nt < 8; ++nt) {
                half8_t bf = *(const half8_t*)&lB[(nt * 16 + lm) * 136 + k0];
                acc[nt] = __builtin_amdgcn_mfma_f32_16x16x32_f16(a, bf, acc[nt], 0, 0, 0);
            }
        }
        // store: g = ct; value (t, b, c = ct*128 + nt*16 + lm)
        // addr f16: (((d*16+bg)*T + t)*4 + ct)*512 + nt*64 + m*16 + lm
#pragma unroll
        for (int nt = 0; nt < 8; ++nt) {
            float bv = bias[ct * 128 + nt * 16 + lm];
#pragma unroll
            for (int rr = 0; rr < 4; ++rr) {
                int t = t0 + w1 * 16 + q * 4 + rr;
                size_t oi = (((size_t)(d * 16 + bg) * T_SEQ + t) * 4 + ct) * 512
                            + nt * 64 + m * 16 + lm;
                zx[oi] = (_Float16)(acc[nt][rr] + bv);
            }
        }
        __syncthreads();   // before restaging lB
    }
}

// ---------------- Phase 2: recurrence ----------------
// grid: (32 batch-pairs, 2 dirs), block 256 (4 waves, 1 wave/SIMD).
// Wave w owns units w*32 + ct*16 + lm (ct = q>>1), batch parity p = q&1.
// MFMA A rows are batch-replicated mod 2 => every lane gets its own cell.
__global__ __launch_bounds__(256, 1) void lstm_rec(
    const float* __restrict__ Wfw, const float* __restrict__ Wbw,
    const _Float16* __restrict__ zx, float* __restrict__ out) {
    const int bgp = blockIdx.x;           // 0..31 batch pair
    const int d = blockIdx.y;             // 0..1
    const float* Wd = d ? Wbw : Wfw;
    const int tid = threadIdx.x;
    const int w = tid >> 6, lane = tid & 63, lm = lane & 15, q = lane >> 4;
    const int p = q & 1;                  // batch within pair
    const int ct = q >> 1;                // which 16-col tile holds this lane's unit
    const int u = w * 32 + ct * 16 + lm;  // unit 0..127

    __shared__ _Float16 hbuf[2][256];     // [buf][batch*128 + unit], stride 128:
                                          // A-frag read is exact 2-way alias (free)

    // Wh B-fragments: bfr[g][c2][ks], col = g*128 + w*32 + c2*16 + lm,
    //                 k = 128 + ks*32 + q*8 + j   (128 VGPRs, loaded once)
    half8_t bfr[4][2][4];
#pragma unroll
    for (int g = 0; g < 4; ++g)
#pragma unroll
        for (int c2 = 0; c2 < 2; ++c2)
#pragma unroll
            for (int ks = 0; ks < 4; ++ks) {
                int col = g * 128 + w * 32 + c2 * 16 + lm;
                int kb = 128 + ks * 32 + q * 8;
                half8_t f;
#pragma unroll
                for (int j = 0; j < 8; ++j)
                    f[j] = (_Float16)Wd[(size_t)(kb + j) * GDIM + col];
                bfr[g][c2][ks] = f;
            }

    for (int i = tid; i < 2 * 256; i += 256) ((_Float16*)hbuf)[i] = (_Float16)0.f;

    // zx prefetch pipeline, depth 3. Layout: [d*16+bg][t][g][u>>4][m][u&15] f16,
    // with bg = bgp>>1, m = (bgp&1)*2 + p  (layout identical to phase 1's store).
    const int bg = bgp >> 1, m = (bgp & 1) * 2 + p;
    const _Float16* zb = zx + (size_t)(d * 16 + bg) * T_SEQ * 2048
                         + (w * 2 + ct) * 64 + m * 16 + lm;
    _Float16 n1[4], n2[4], n3[4];
    {
        int t0 = d ? (T_SEQ - 1) : 0;
        int t1 = d ? (T_SEQ - 2) : 1;
        int t2 = d ? (T_SEQ - 3) : 2;
#pragma unroll
        for (int g = 0; g < 4; ++g) n1[g] = zb[(size_t)t0 * 2048 + g * 512];
#pragma unroll
        for (int g = 0; g < 4; ++g) n2[g] = zb[(size_t)t1 * 2048 + g * 512];
#pragma unroll
        for (int g = 0; g < 4; ++g) n3[g] = zb[(size_t)t2 * 2048 + g * 512];
    }
    float cst = 0.f;
    const int b_out = bgp * 2 + p;
    __syncthreads();

    for (int s = 0; s < T_SEQ; ++s) {
        const int t = d ? (T_SEQ - 1 - s) : s;
        const _Float16* hr = hbuf[s & 1];
        _Float16* hw = hbuf[(s + 1) & 1];

        // A-fragments: A[row][k] = h[row&1][k] (batch-replicated rows)
        half8_t af[4];
#pragma unroll
        for (int ks = 0; ks < 4; ++ks)
            af[ks] = *(const half8_t*)&hr[(lm & 1) * 128 + ks * 32 + q * 8];

        // rotate zx pipeline; issue prefetch for s+3 (stays in flight across barrier)
        float zc[4];
#pragma unroll
        for (int g = 0; g < 4; ++g) { zc[g] = (float)n1[g]; n1[g] = n2[g]; n2[g] = n3[g]; }
        int sn = (s + 3 < T_SEQ) ? s + 3 : T_SEQ - 1;
        int tn = d ? (T_SEQ - 1 - sn) : sn;
#pragma unroll
        for (int g = 0; g < 4; ++g) n3[g] = zb[(size_t)tn * 2048 + g * 512];

        floatx4 acg[4][2];
#pragma unroll
        for (int g = 0; g < 4; ++g) {
            acg[g][0] = (floatx4){0.f, 0.f, 0.f, 0.f};
            acg[g][1] = (floatx4){0.f, 0.f, 0.f, 0.f};
        }
#pragma unroll
        for (int ks = 0; ks < 4; ++ks)
#pragma unroll
            for (int g = 0; g < 4; ++g) {
                acg[g][0] = __builtin_amdgcn_mfma_f32_16x16x32_f16(af[ks], bfr[g][0][ks], acg[g][0], 0, 0, 0);
                acg[g][1] = __builtin_amdgcn_mfma_f32_16x16x32_f16(af[ks], bfr[g][1][ks], acg[g][1], 0, 0, 0);
            }

        // every lane: one cell (batch p, unit u)
        float zi = selz(acg[0][0], acg[0][1], ct, p) + zc[0];
        float zj = selz(acg[1][0], acg[1][1], ct, p) + zc[1];
        float zf = selz(acg[2][0], acg[2][1], ct, p) + zc[2];
        float zo = selz(acg[3][0], acg[3][1], ct, p) + zc[3];
        cst = cst * sigm_f(zf + 1.0f) + sigm_f(zi) * tanh_f(zj);
        float h = sigm_f(zo) * tanh_f(cst);

        hw[p * 128 + u] = (_Float16)h;
        out[((size_t)b_out * T_SEQ + t) * 256 + d * 128 + u] = h;

        // LDS-only barrier: drain lgkm (h write) but leave vmcnt (zx prefetch,
        // out stores) in flight.
        asm volatile("s_waitcnt lgkmcnt(0)\n\ts_barrier" ::: "memory");
    }
}

extern "C" void kernel_launch(void* const* d_in, const int* in_sizes, int n_in,
                              void* d_out, int out_size, void* d_ws, size_t ws_size,
                              hipStream_t stream) {
    const float* x   = (const float*)d_in[0];
    const float* Wfw = (const float*)d_in[1];
    const float* bfw = (const float*)d_in[2];
    const float* Wbw = (const float*)d_in[3];
    const float* bbw = (const float*)d_in[4];
    float* out = (float*)d_out;
    _Float16* zx = (_Float16*)d_ws;  // 2*16*2048*2048*2B = 256 MiB

    dim3 g1(32, 64, 2);
    zx_gemm<<<g1, 256, 0, stream>>>(x, Wfw, bfw, Wbw, bbw, zx);
    dim3 g2(32, 2);
    lstm_rec<<<g2, 256, 0, stream>>>(Wfw, Wbw, zx, out);
}

// Round 3
// 1615.483 us; speedup vs baseline: 1.1646x; 1.1646x over previous
//
#include <hip/hip_runtime.h>
#include <hip/hip_bf16.h>

// BiLSTM: B=64, T=2048, F=128, U=128. fp32 in/out.
// Phase 1: zx[d][bg][t][g][w][L] (f16) = x@Wx + b, L = m*16+ulocal (m=b&3).
// Phase 2: 32 WGs (2 dir x 16 batch-groups of 4), 8 waves each (2/SIMD).
//          Per step: lgkm-ONLY barrier built from bare s_waitcnt asm (NO
//          "memory" clobber!) + __builtin s_barrier, fenced by sched_barrier.
//          A "memory"-clobber asm is modeled mayLoad/mayStore and forces the
//          waitcnt pass to drain vmcnt(0) every step -> exposes one full HBM
//          round trip per step (~900 cyc). This version keeps the zx prefetch
//          (depth 3) and out stores genuinely in flight across the barrier.

typedef _Float16 half8_t __attribute__((ext_vector_type(8)));
typedef _Float16 half4_t __attribute__((ext_vector_type(4)));
typedef float floatx4 __attribute__((ext_vector_type(4)));

#define T_SEQ 2048
#define GDIM 512

__device__ __forceinline__ float sigm_f(float x) {
    return __builtin_amdgcn_rcpf(1.0f + __expf(-x));
}
__device__ __forceinline__ float tanh_f(float x) {
    return 1.0f - 2.0f * __builtin_amdgcn_rcpf(1.0f + __expf(2.0f * x));
}
__device__ __forceinline__ float sel4(floatx4 v, int m) {
    float a = (m & 1) ? v[1] : v[0];
    float b = (m & 1) ? v[3] : v[2];
    return (m & 2) ? b : a;
}

// ---------------- Phase 1: Zx GEMM (unchanged) ----------------
// grid: (32 ttiles, 64 batches, 2 dirs), block 256. A staged once; 4 ctile passes.
__global__ __launch_bounds__(256) void zx_gemm(
    const float* __restrict__ x,
    const float* __restrict__ Wfw, const float* __restrict__ bfw,
    const float* __restrict__ Wbw, const float* __restrict__ bbw,
    _Float16* __restrict__ zx) {
    const int tid = threadIdx.x;
    const int tt = blockIdx.x;           // 0..31
    const int b = blockIdx.y;            // batch
    const int d = blockIdx.z;            // dir
    const int t0 = tt * 64;
    const float* W = d ? Wbw : Wfw;
    const float* bias = d ? bbw : bfw;
    const int bg = b >> 2, m = b & 3;

    __shared__ _Float16 lA[64 * 136];
    __shared__ _Float16 lB[128 * 136];

    // stage A = x[b, t0..t0+63, 0..127] -> lA[row][k]
    const float* xp = x + ((size_t)b * T_SEQ + t0) * 128;
    for (int i = 0; i < 8; ++i) {
        int v = i * 256 + tid;
        int r = v >> 5;
        int kq = (v & 31) << 2;
        float4 f = *(const float4*)(xp + r * 128 + kq);
        half4_t h4;
        h4[0] = (_Float16)f.x; h4[1] = (_Float16)f.y;
        h4[2] = (_Float16)f.z; h4[3] = (_Float16)f.w;
        *(half4_t*)&lA[r * 136 + kq] = h4;
    }

    const int w1 = tid >> 6, lane = tid & 63, lm = lane & 15, q = lane >> 4;

    for (int ct = 0; ct < 4; ++ct) {
        // stage B = W[0..127, ct*128 .. +128) transposed -> lB[col][k]
        const float* wp = W + ct * 128;
        for (int i = 0; i < 16; ++i) {
            int v = i * 256 + tid;
            int k = v >> 5;
            int cq = (v & 31) << 2;
            float4 f = *(const float4*)(wp + (size_t)k * GDIM + cq);
            lB[(cq + 0) * 136 + k] = (_Float16)f.x;
            lB[(cq + 1) * 136 + k] = (_Float16)f.y;
            lB[(cq + 2) * 136 + k] = (_Float16)f.z;
            lB[(cq + 3) * 136 + k] = (_Float16)f.w;
        }
        __syncthreads();

        floatx4 acc[8];
#pragma unroll
        for (int nt = 0; nt < 8; ++nt) acc[nt] = (floatx4){0.f, 0.f, 0.f, 0.f};
#pragma unroll
        for (int ks = 0; ks < 4; ++ks) {
            const int k0 = ks * 32 + q * 8;
            half8_t a = *(const half8_t*)&lA[(w1 * 16 + lm) * 136 + k0];
#pragma unroll
            for (int nt = 0; nt < 8; ++nt) {
                half8_t bf = *(const half8_t*)&lB[(nt * 16 + lm) * 136 + k0];
                acc[nt] = __builtin_amdgcn_mfma_f32_16x16x32_f16(a, bf, acc[nt], 0, 0, 0);
            }
        }
        // store: g = ct; value (t, b, c = ct*128 + nt*16 + lm)
        // addr f16: (((d*16+bg)*T + t)*4 + ct)*512 + nt*64 + m*16 + lm
#pragma unroll
        for (int nt = 0; nt < 8; ++nt) {
            float bv = bias[ct * 128 + nt * 16 + lm];
#pragma unroll
            for (int rr = 0; rr < 4; ++rr) {
                int t = t0 + w1 * 16 + q * 4 + rr;
                size_t oi = (((size_t)(d * 16 + bg) * T_SEQ + t) * 4 + ct) * 512
                            + nt * 64 + m * 16 + lm;
                zx[oi] = (_Float16)(acc[nt][rr] + bv);
            }
        }
        __syncthreads();   // before restaging lB
    }
}

// ---------------- Phase 2: recurrence ----------------
// grid: (16 batch-groups, 2 dirs), block 512 (8 waves, 2/SIMD).
// Wave w owns cols {g*128 + w*16 + lm}, g=0..3 (in-wave gates).
__global__ __launch_bounds__(512) void lstm_rec(
    const float* __restrict__ Wfw, const float* __restrict__ Wbw,
    const _Float16* __restrict__ zx, float* __restrict__ out) {
    const int bg = blockIdx.x;            // 0..15
    const int d = blockIdx.y;             // 0..1
    const int b0 = bg * 4;
    const float* Wd = d ? Wbw : Wfw;
    const int tid = threadIdx.x;
    const int w = tid >> 6, lane = tid & 63, lm = lane & 15, q = lane >> 4;
    const int m = q;                      // batch slot this lane's gate cell uses

    __shared__ _Float16 hbuf[2][4 * 136]; // double-buffered h, rows = batch 0..3
                                          // stride 136: 4-row A-frag read spreads
                                          // banks (stride 128 would be 4-way)

    // Wh B-fragments: bfr[g][ks], col = g*128 + w*16 + lm, k = 128 + ks*32 + q*8
    half8_t bfr[4][4];
#pragma unroll
    for (int g = 0; g < 4; ++g)
#pragma unroll
        for (int ks = 0; ks < 4; ++ks) {
            int col = g * 128 + w * 16 + lm;
            int kb = 128 + ks * 32 + q * 8;
            half8_t f;
#pragma unroll
            for (int j = 0; j < 8; ++j)
                f[j] = (_Float16)Wd[(size_t)(kb + j) * GDIM + col];
            bfr[g][ks] = f;
        }

    for (int i = tid; i < 2 * 4 * 136; i += 512) ((_Float16*)hbuf)[i] = (_Float16)0.f;

    // zx prefetch pipeline, depth 3. Layout: [d*16+bg][t][g][w][lane] f16.
    const _Float16* zb = zx + (size_t)(d * 16 + bg) * T_SEQ * 2048 + w * 64 + lane;
    _Float16 n1[4], n2[4], n3[4];
    {
        int ta = d ? (T_SEQ - 1) : 0;
        int tb = d ? (T_SEQ - 2) : 1;
        int tc = d ? (T_SEQ - 3) : 2;
#pragma unroll
        for (int g = 0; g < 4; ++g) n1[g] = zb[(size_t)ta * 2048 + g * 512];
#pragma unroll
        for (int g = 0; g < 4; ++g) n2[g] = zb[(size_t)tb * 2048 + g * 512];
#pragma unroll
        for (int g = 0; g < 4; ++g) n3[g] = zb[(size_t)tc * 2048 + g * 512];
    }
    float cst = 0.f;
    __syncthreads();

    for (int s = 0; s < T_SEQ; ++s) {
        const int t = d ? (T_SEQ - 1 - s) : s;
        const _Float16* hr = hbuf[s & 1];
        _Float16* hw = hbuf[(s + 1) & 1];

        // A-fragments: A[row][k] = h[row&3][k] (row-replicated)
        half8_t af[4];
#pragma unroll
        for (int ks = 0; ks < 4; ++ks)
            af[ks] = *(const half8_t*)&hr[(lm & 3) * 136 + ks * 32 + q * 8];

        // rotate zx pipeline; issue prefetch for s+3 (stays in flight across barrier)
        float zc[4];
#pragma unroll
        for (int g = 0; g < 4; ++g) { zc[g] = (float)n1[g]; n1[g] = n2[g]; n2[g] = n3[g]; }
        int sn = (s + 3 < T_SEQ) ? s + 3 : T_SEQ - 1;
        int tn = d ? (T_SEQ - 1 - sn) : sn;
#pragma unroll
        for (int g = 0; g < 4; ++g) n3[g] = zb[(size_t)tn * 2048 + g * 512];

        floatx4 acg[4];
#pragma unroll
        for (int g = 0; g < 4; ++g) acg[g] = (floatx4){0.f, 0.f, 0.f, 0.f};
#pragma unroll
        for (int ks = 0; ks < 4; ++ks)
#pragma unroll
            for (int g = 0; g < 4; ++g)
                acg[g] = __builtin_amdgcn_mfma_f32_16x16x32_f16(af[ks], bfr[g][ks], acg[g], 0, 0, 0);

        // every lane: one cell (batch m = q, u = w*16 + lm); regs hold all 4 batches
        float zi = sel4(acg[0], m) + zc[0];
        float zj = sel4(acg[1], m) + zc[1];
        float zf = sel4(acg[2], m) + zc[2];
        float zo = sel4(acg[3], m) + zc[3];
        cst = cst * sigm_f(zf + 1.0f) + sigm_f(zi) * tanh_f(zj);
        float h = sigm_f(zo) * tanh_f(cst);

        hw[m * 136 + w * 16 + lm] = (_Float16)h;
        out[((size_t)(b0 + m) * T_SEQ + t) * 256 + d * 128 + w * 16 + lm] = h;

        // LDS-only barrier. NO "memory" clobber anywhere here: a memory-clobber
        // asm is treated as mayLoad/mayStore and makes the waitcnt pass drain
        // vmcnt(0) each step (kills the prefetch). sched_barrier(0) pins the
        // ds_write above the wait and the next iteration's ds_read below the
        // barrier (rule: compiler may otherwise move mem ops across bare asm).
        __builtin_amdgcn_sched_barrier(0);
        asm volatile("s_waitcnt lgkmcnt(0)");
        __builtin_amdgcn_s_barrier();
        __builtin_amdgcn_sched_barrier(0);
    }
}

extern "C" void kernel_launch(void* const* d_in, const int* in_sizes, int n_in,
                              void* d_out, int out_size, void* d_ws, size_t ws_size,
                              hipStream_t stream) {
    const float* x   = (const float*)d_in[0];
    const float* Wfw = (const float*)d_in[1];
    const float* bfw = (const float*)d_in[2];
    const float* Wbw = (const float*)d_in[3];
    const float* bbw = (const float*)d_in[4];
    float* out = (float*)d_out;
    _Float16* zx = (_Float16*)d_ws;  // 2*16*2048*2048*2B = 256 MiB

    dim3 g1(32, 64, 2);
    zx_gemm<<<g1, 256, 0, stream>>>(x, Wfw, bfw, Wbw, bbw, zx);
    dim3 g2(16, 2);
    lstm_rec<<<g2, 512, 0, stream>>>(Wfw, Wbw, zx, out);
}